// Round 3
// baseline (632.668 us; speedup 1.0000x reference)
//
#include <hip/hip_runtime.h>

// SelfAttention (Galerkin linear attention), round 5.
// Algebra: qk_in = x + pos ; K = qk_in Wk^T + bk ; V = x Wv^T + bv
//          (per-head LN on K,V) ; S'_h = K_h^T V_h / n
//          W2[he][r] = sum_d Wq[hd][r] S'[d][e] ; b2[he] = sum_d bq[hd] S'[d][e]
//          out = LN(2*(qk_in W2^T + b2)) stored NCHW.
// R5 key insight: pos[n][k] is separable — k<128 depends only on i=n>>7,
//   k>=128 only on j=n&127. So pos @ W^T = PyW[i][oc] + PxW[j][oc] with two
//   128x256 f32 tables per W. We therefore stage ONLY xT=bf16(x):
//     V = x Wv^T + bv                      (exact, unchanged)
//     K = x Wk^T + (PyK[i]+PxK[j])        (bk folded into PyK; f32 tables)
//     out-GEMM = x W2^T + (Py2[i]+Px2[j]) (b2 folded into Py2)
//   Halves prep write (64 MB), halves kv staging (one stream, A-frag reused
//   by K0/K1/V0/V1 MFMAs), removes all trig from prep.
// R5 pipelining: stage s+1 issued AFTER B-frag loads (in-order vmcnt: B-wait
//   then doesn't wait the stage) and BEFORE the MFMA phase; drain happens at
//   the NEXT barrier after ~300-500cy of MFMA. Quarter relayout (LDC2=40,
//   16B-aligned rows) shrinks LDS to 53248 B.

typedef float floatx4 __attribute__((ext_vector_type(4)));
typedef __bf16 bf16x8 __attribute__((ext_vector_type(8)));
typedef unsigned short ushortx8 __attribute__((ext_vector_type(8)));
typedef unsigned short ushort;

static __device__ __forceinline__ ushort f2bf(float f) {
  unsigned int u = __builtin_bit_cast(unsigned int, f);
  u += 0x7FFFu + ((u >> 16) & 1u);  // RNE
  return (ushort)(u >> 16);
}
static __device__ __forceinline__ floatx4 mfma16(bf16x8 a, bf16x8 b, floatx4 c) {
  return __builtin_amdgcn_mfma_f32_16x16x32_bf16(a, b, c, 0, 0, 0);
}
static __device__ __forceinline__ bf16x8 frag(const ushort* p) {
  return *(const bf16x8*)p;  // 16-B aligned by construction -> dwordx4
}
typedef __attribute__((address_space(3))) unsigned int as3_u32;
typedef __attribute__((address_space(1))) const unsigned int as1_u32;
static __device__ __forceinline__ void gl_lds16(const ushort* g, ushort* l) {
  __builtin_amdgcn_global_load_lds((as1_u32*)g, (as3_u32*)l, 16, 0, 0);
}

// ---------------------------------------------------------------------------
// Wk, Wv fp32 -> bf16 (plain [oc][256]).
__global__ __launch_bounds__(256) void prep_w(const float* __restrict__ Wk,
                                              const float* __restrict__ Wv,
                                              ushort* __restrict__ Wkbf,
                                              ushort* __restrict__ Wvbf) {
  const int i = (int)blockIdx.x * 256 + (int)threadIdx.x;
  float4 a = ((const float4*)Wk)[i];
  float4 b = ((const float4*)Wv)[i];
  ushort4 ua = {f2bf(a.x), f2bf(a.y), f2bf(a.z), f2bf(a.w)};
  ushort4 ub = {f2bf(b.x), f2bf(b.y), f2bf(b.z), f2bf(b.w)};
  ((ushort4*)Wkbf)[i] = ua;
  ((ushort4*)Wvbf)[i] = ub;
}

// ---------------------------------------------------------------------------
// Pos tables for K: PyKb[i][oc] = bk[oc] + sum_{kk<128} pe(i,kk)*Wk[oc][kk]
//                   PxKT[oc][j] =          sum_{kk<128} pe(j,kk)*Wk[oc][128+kk]
// pe(idx,kk): coord=(idx+1)*2pi/(128+1e-6), inv=10000^-((kk>>1)/64),
//             pe = (kk&1) ? cos(coord*inv) : sin(coord*inv).
__global__ __launch_bounds__(256) void poswk(const float* __restrict__ Wk,
                                             const float* __restrict__ bk,
                                             float* __restrict__ PyKb,
                                             float* __restrict__ PxKT) {
  __shared__ float pe[128];
  const int ii = (int)blockIdx.x, t = (int)threadIdx.x;
  if (t < 128) {
    const float coord = (float)(ii + 1) * (6.283185307179586f / (128.0f + 1e-6f));
    const float inv = exp2f(-13.287712379549449f * (float)(t >> 1) * (1.0f / 64.0f));
    const float arg = coord * inv;
    pe[t] = (t & 1) ? cosf(arg) : sinf(arg);
  }
  __syncthreads();
  const float* wrow = Wk + (size_t)t * 256;
  float py = bk[t], px = 0.0f;
#pragma unroll 8
  for (int kk = 0; kk < 128; ++kk) {
    py += pe[kk] * wrow[kk];
    px += pe[kk] * wrow[128 + kk];
  }
  PyKb[ii * 256 + t] = py;
  PxKT[t * 128 + ii] = px;
}

// ---------------------------------------------------------------------------
// Pos tables for W2 (per z): Py2b[z][i][e] = b2[z][e] + pos_y(i) @ W2f[z][e][:128]
//                            Px2T[z][e][j] =            pos_x(j) @ W2f[z][e][128:]
__global__ __launch_bounds__(256) void posw2(const float* __restrict__ W2f,
                                             const float* __restrict__ b2,
                                             float* __restrict__ Py2b,
                                             float* __restrict__ Px2T) {
  __shared__ float pe[128];
  const int ii = (int)blockIdx.x, z = (int)blockIdx.y, t = (int)threadIdx.x;
  if (t < 128) {
    const float coord = (float)(ii + 1) * (6.283185307179586f / (128.0f + 1e-6f));
    const float inv = exp2f(-13.287712379549449f * (float)(t >> 1) * (1.0f / 64.0f));
    const float arg = coord * inv;
    pe[t] = (t & 1) ? cosf(arg) : sinf(arg);
  }
  __syncthreads();
  const float* wrow = W2f + (size_t)z * 65536 + (size_t)t * 256;
  float py = b2[z * 256 + t], px = 0.0f;
#pragma unroll 8
  for (int kk = 0; kk < 128; ++kk) {
    py += pe[kk] * wrow[kk];
    px += pe[kk] * wrow[128 + kk];
  }
  Py2b[((size_t)z * 128 + ii) * 256 + t] = py;
  Px2T[(size_t)z * 32768 + t * 128 + ii] = px;
}

// ---------------------------------------------------------------------------
// For batch b0+z: xT[z][n][k] = bf16(x) only (no pos — handled by tables).
// SWIZZLED store: 16B sub-chunk p stored at p ^ (n&7) within each 64-k group.
__global__ __launch_bounds__(256) void prep_qx(const float* __restrict__ x,
                                               ushort* __restrict__ xT, int b0) {
  __shared__ float tile[64 * 68];
  const int t = (int)threadIdx.x;
  const int z = (int)blockIdx.y;
  const int b = b0 + z;
  const int n0 = (int)blockIdx.x * 64;
  const float* xb = x + (size_t)b * 256 * 16384;
  ushort* xtb = xT + (size_t)z * 16384 * 256;
  for (int kc = 0; kc < 4; ++kc) {
    if (kc) __syncthreads();
    const int nn = (t & 15) * 4;
    const int r0 = t >> 4;
#pragma unroll
    for (int it = 0; it < 4; ++it) {
      const int k = r0 + it * 16;
      const float4 v = *(const float4*)(xb + (size_t)(kc * 64 + k) * 16384 + n0 + nn);
      tile[(nn + 0) * 68 + k] = v.x;
      tile[(nn + 1) * 68 + k] = v.y;
      tile[(nn + 2) * 68 + k] = v.z;
      tile[(nn + 3) * 68 + k] = v.w;
    }
    __syncthreads();
#pragma unroll
    for (int it = 0; it < 2; ++it) {
      const int P = t + it * 256;
      const int r = P >> 3;  // n row 0..63
      const int p = P & 7;   // k chunk of 8
      const int n = n0 + r;
      ushortx8 ux;
#pragma unroll
      for (int e = 0; e < 8; ++e) ux[e] = f2bf(tile[r * 68 + p * 8 + e]);
      const int sw = (p ^ (r & 7)) * 8;
      *(ushortx8*)(xtb + (size_t)n * 256 + kc * 64 + sw) = ux;
    }
  }
}

// ---------------------------------------------------------------------------
// Per block: (4 x 128-n tiles, hv, z). Wave w owns head hv*4+w.
// Single xT stream staged double-buffered via global_load_lds; A-frag reused
// by K0/K1/V0/V1 MFMAs. K gets f32 pos+bias table correction pre-LN.
// Quarter-sized K^T/V^T relayout (32 rows, LDC2=40 -> 80B rows, 16B aligned).
#define LDC2 40
__global__ __launch_bounds__(256, 2) void kv_scores(
    const ushort* __restrict__ xT, const ushort* __restrict__ Wkbf,
    const ushort* __restrict__ Wvbf, const float* __restrict__ bv,
    const float* __restrict__ gK, const float* __restrict__ bKp,
    const float* __restrict__ gV, const float* __restrict__ bVp,
    const float* __restrict__ PyKb, const float* __restrict__ PxKT,
    float* __restrict__ scores) {
  __shared__ ushort SQ[2][128 * 64];  // staged xT k-chunks (swizzled), dbuf
  __shared__ ushort KT[128 * LDC2];
  __shared__ ushort VT[128 * LDC2];
  const int t = (int)threadIdx.x, lane = t & 63, w = t >> 6;
  const int l15 = lane & 15, l4 = lane >> 4;
  const int hv = (int)blockIdx.y, z = (int)blockIdx.z;
  const int bx = (int)blockIdx.x;
  const ushort* xb = xT + (size_t)z * 16384 * 256;
  const int ocb = hv * 128 + w * 32;
  const int h = hv * 4 + w;
  const float bvv0 = bv[ocb + l15], bvv1 = bv[ocb + 16 + l15];
  const float gk0 = gK[h * 32 + l15], gk1 = gK[h * 32 + 16 + l15];
  const float ok0 = bKp[h * 32 + l15], ok1 = bKp[h * 32 + 16 + l15];
  const float gv0 = gV[h * 32 + l15], gv1 = gV[h * 32 + 16 + l15];
  const float ov0 = bVp[h * 32 + l15], ov1 = bVp[h * 32 + 16 + l15];
  const int srow = w * 32 + (lane >> 3);
  const int scol = (lane & 7) * 8;
  const int rsw = l15 & 7;

  auto issue = [&](int s) {
    const int n0s = (bx * 4 + (s >> 2)) * 128;
    const int kcs = (s & 3) * 64;
    ushort* dst = &SQ[s & 1][w * 2048];
    const ushort* src = xb + (size_t)(n0s + srow) * 256 + kcs + scol;
#pragma unroll
    for (int j = 0; j < 4; ++j) gl_lds16(src + (size_t)j * 8 * 256, dst + j * 512);
  };
  issue(0);

  floatx4 sacc[2][2] = {};
  for (int nt = 0; nt < 4; ++nt) {
    const int i_nt = bx * 4 + nt;
    floatx4 acck[2][8] = {};
    floatx4 accv[2][8] = {};
    float py0 = 0.f, py1 = 0.f;
    float4 pxq0[2][2];  // q=0 tables preloaded at kc==3 (before stage issue)
    for (int kc = 0; kc < 4; ++kc) {
      const int s = nt * 4 + kc;
      __syncthreads();  // drains stage s; protects buf (s+1)&1 overwrite
      // B-frags first (L2): in-order vmcnt means waiting on these does not
      // wait on the stage issued below.
      bf16x8 Bk0[2], Bk1[2], Bv0[2], Bv1[2];
#pragma unroll
      for (int ci = 0; ci < 2; ++ci) {
        const int kb = (kc * 2 + ci) * 32 + l4 * 8;
        Bk0[ci] = frag(Wkbf + (ocb + l15) * 256 + kb);
        Bk1[ci] = frag(Wkbf + (ocb + 16 + l15) * 256 + kb);
        Bv0[ci] = frag(Wvbf + (ocb + l15) * 256 + kb);
        Bv1[ci] = frag(Wvbf + (ocb + 16 + l15) * 256 + kb);
      }
      if (kc == 3) {  // preload LN tables used right after this MFMA phase
        py0 = PyKb[i_nt * 256 + ocb + l15];
        py1 = PyKb[i_nt * 256 + ocb + 16 + l15];
#pragma unroll
        for (int mm = 0; mm < 2; ++mm) {
          pxq0[0][mm] = *(const float4*)(PxKT + (ocb + l15) * 128 + mm * 16 + l4 * 4);
          pxq0[1][mm] = *(const float4*)(PxKT + (ocb + 16 + l15) * 128 + mm * 16 + l4 * 4);
        }
      }
      if (s < 15) issue(s + 1);  // drain lands at NEXT barrier, after MFMAs
      const ushort* sq = &SQ[s & 1][0];
#pragma unroll
      for (int ci = 0; ci < 2; ++ci) {
#pragma unroll
        for (int m = 0; m < 8; ++m) {
          const int off = (m * 16 + l15) * 64 + ((ci * 4 + l4) ^ rsw) * 8;
          const bf16x8 a = *(const bf16x8*)(sq + off);
          acck[0][m] = mfma16(a, Bk0[ci], acck[0][m]);
          acck[1][m] = mfma16(a, Bk1[ci], acck[1][m]);
          accv[0][m] = mfma16(a, Bv0[ci], accv[0][m]);
          accv[1][m] = mfma16(a, Bv1[ci], accv[1][m]);
        }
      }
    }
    // LN + quarter relayout + S-MFMA (q covers m = 2q, 2q+1 -> 32 n-rows)
#pragma unroll
    for (int q = 0; q < 4; ++q) {
#pragma unroll
      for (int mm = 0; mm < 2; ++mm) {
        const int m = q * 2 + mm;
        float4 px0, px1;
        if (q == 0) {
          px0 = pxq0[0][mm];
          px1 = pxq0[1][mm];
        } else {
          px0 = *(const float4*)(PxKT + (ocb + l15) * 128 + m * 16 + l4 * 4);
          px1 = *(const float4*)(PxKT + (ocb + 16 + l15) * 128 + m * 16 + l4 * 4);
        }
        const float px0a[4] = {px0.x, px0.y, px0.z, px0.w};
        const float px1a[4] = {px1.x, px1.y, px1.z, px1.w};
#pragma unroll
        for (int r = 0; r < 4; ++r) {
          {
            const float a0 = acck[0][m][r] + py0 + px0a[r];
            const float a1 = acck[1][m][r] + py1 + px1a[r];
            float sum = a0 + a1, sq2 = a0 * a0 + a1 * a1;
#pragma unroll
            for (int msk = 1; msk < 16; msk <<= 1) {
              sum += __shfl_xor(sum, msk);
              sq2 += __shfl_xor(sq2, msk);
            }
            const float mu = sum * (1.0f / 32.0f);
            const float rstd = rsqrtf(sq2 * (1.0f / 32.0f) - mu * mu + 1e-5f);
            acck[0][m][r] = (a0 - mu) * rstd * gk0 + ok0;
            acck[1][m][r] = (a1 - mu) * rstd * gk1 + ok1;
          }
          {
            const float a0 = accv[0][m][r] + bvv0;
            const float a1 = accv[1][m][r] + bvv1;
            float sum = a0 + a1, sq2 = a0 * a0 + a1 * a1;
#pragma unroll
            for (int msk = 1; msk < 16; msk <<= 1) {
              sum += __shfl_xor(sum, msk);
              sq2 += __shfl_xor(sq2, msk);
            }
            const float mu = sum * (1.0f / 32.0f);
            const float rstd = rsqrtf(sq2 * (1.0f / 32.0f) - mu * mu + 1e-5f);
            accv[0][m][r] = (a0 - mu) * rstd * gv0 + ov0;
            accv[1][m][r] = (a1 - mu) * rstd * gv1 + ov1;
          }
        }
      }
      __syncthreads();  // prior S-MFMA/stage reads done; safe to overwrite KT/VT
#pragma unroll
      for (int tt = 0; tt < 2; ++tt) {
        const int ch = w * 32 + tt * 16 + l15;
#pragma unroll
        for (int mm = 0; mm < 2; ++mm) {
          const int m = q * 2 + mm;
          const int col = mm * 16 + l4 * 4;
          ushort4 uk = {f2bf(acck[tt][m][0]), f2bf(acck[tt][m][1]),
                        f2bf(acck[tt][m][2]), f2bf(acck[tt][m][3])};
          ushort4 uv = {f2bf(accv[tt][m][0]), f2bf(accv[tt][m][1]),
                        f2bf(accv[tt][m][2]), f2bf(accv[tt][m][3])};
          *(ushort4*)(KT + ch * LDC2 + col) = uk;
          *(ushort4*)(VT + ch * LDC2 + col) = uv;
        }
      }
      __syncthreads();
      const int ko = l4 * 8;
      const bf16x8 ka0 = *(const bf16x8*)(KT + (w * 32 + l15) * LDC2 + ko);
      const bf16x8 ka1 = *(const bf16x8*)(KT + (w * 32 + 16 + l15) * LDC2 + ko);
      const bf16x8 vb0 = *(const bf16x8*)(VT + (w * 32 + l15) * LDC2 + ko);
      const bf16x8 vb1 = *(const bf16x8*)(VT + (w * 32 + 16 + l15) * LDC2 + ko);
      sacc[0][0] = mfma16(ka0, vb0, sacc[0][0]);
      sacc[0][1] = mfma16(ka0, vb1, sacc[0][1]);
      sacc[1][0] = mfma16(ka1, vb0, sacc[1][0]);
      sacc[1][1] = mfma16(ka1, vb1, sacc[1][1]);
    }
  }
#pragma unroll
  for (int di = 0; di < 2; ++di)
#pragma unroll
    for (int ej = 0; ej < 2; ++ej)
#pragma unroll
      for (int r = 0; r < 4; ++r) {
        const int d = di * 16 + l4 * 4 + r;
        const int e = ej * 16 + l15;
        atomicAdd(scores + ((size_t)(z * 8 + h) * 32 + d) * 32 + e, sacc[di][ej][r]);
      }
}

// ---------------------------------------------------------------------------
// W2bf/W2f[z][he][r] = sum_d Wq[hd][r] S'[d][e] / n ; b2 = bq-fold / n.
__global__ __launch_bounds__(256) void w2_kernel(
    const float* __restrict__ Wq, const float* __restrict__ bq,
    const float* __restrict__ scores, ushort* __restrict__ W2bf,
    float* __restrict__ W2f, float* __restrict__ b2) {
  const int z = (int)blockIdx.y;
  const int row = (int)blockIdx.x;
  const int t = (int)threadIdx.x;
  const float inv_n = 1.0f / 16384.0f;
  const float* sc = scores + (size_t)z * 8192;
  if (row < 256) {
    const int h = row >> 5, e = row & 31;
    float s = 0.0f;
#pragma unroll
    for (int d = 0; d < 32; ++d)
      s += Wq[(h * 32 + d) * 256 + t] * sc[(h * 32 + d) * 32 + e];
    const float v = s * inv_n;
    W2bf[(size_t)z * 65536 + row * 256 + t] = f2bf(v);
    W2f[(size_t)z * 65536 + row * 256 + t] = v;
  } else {
    const int h = t >> 5, e = t & 31;
    float s = 0.0f;
#pragma unroll
    for (int d = 0; d < 32; ++d)
      s += bq[h * 32 + d] * sc[(h * 32 + d) * 32 + e];
    b2[z * 256 + t] = s * inv_n;
  }
}

// ---------------------------------------------------------------------------
// out = LN(2*(x W2^T + Py2[i] + Px2[j])) stored NCHW (b2 folded into Py2).
// xT is XOR-swizzled: sub-chunk lc read at lc ^ (row&7).
__global__ __launch_bounds__(256, 2) void out_kernel(
    const ushort* __restrict__ xT, const ushort* __restrict__ W2bf,
    const float* __restrict__ Py2b, const float* __restrict__ Px2T,
    const float* __restrict__ g_ln, const float* __restrict__ b_ln,
    float* __restrict__ out, int b0) {
  const int t = (int)threadIdx.x, lane = t & 63, w = t >> 6;
  const int l15 = lane & 15, l4 = lane >> 4;
  const int z = (int)blockIdx.y, b = b0 + z;
  const int bx = (int)blockIdx.x;
  const int n0 = bx * 64;
  const ushort* xb = xT + (size_t)z * 16384 * 256;
  const ushort* W2b = W2bf + (size_t)z * 65536;
  const float* py = Py2b + ((size_t)z * 128 + (bx >> 1)) * 256;
  const float* pxT = Px2T + (size_t)z * 32768;
  const int jbase = (bx & 1) * 64 + w * 16 + l4 * 4;
  const int row = n0 + w * 16 + l15;
  const int rsw = l15 & 7;
  floatx4 acc[16] = {};
#pragma unroll
  for (int c = 0; c < 8; ++c) {
    const int kb = c * 32 + l4 * 8;
    const int off = (c >> 1) * 64 + ((((c & 1) * 4 + l4) ^ rsw)) * 8;
    const bf16x8 a = frag(xb + (size_t)row * 256 + off);
#pragma unroll
    for (int tt = 0; tt < 16; ++tt) {
      const bf16x8 bb = frag(W2b + (tt * 16 + l15) * 256 + kb);
      acc[tt] = mfma16(a, bb, acc[tt]);
    }
  }
  // + pos/bias tables, double, LN over 256 channels, NCHW store
#pragma unroll
  for (int tt = 0; tt < 16; ++tt) {
    const int c = tt * 16 + l15;
    const float pyv = py[c];
    const float4 px = *(const float4*)(pxT + c * 128 + jbase);
    const float pxa[4] = {px.x, px.y, px.z, px.w};
#pragma unroll
    for (int r = 0; r < 4; ++r) acc[tt][r] = 2.0f * (acc[tt][r] + pyv + pxa[r]);
  }
  float mean[4], rstd[4];
#pragma unroll
  for (int r = 0; r < 4; ++r) {
    float s = 0.0f, q = 0.0f;
#pragma unroll
    for (int tt = 0; tt < 16; ++tt) {
      const float v = acc[tt][r];
      s += v;
      q += v * v;
    }
#pragma unroll
    for (int msk = 1; msk < 16; msk <<= 1) {
      s += __shfl_xor(s, msk);
      q += __shfl_xor(q, msk);
    }
    const float mu = s * (1.0f / 256.0f);
    mean[r] = mu;
    rstd[r] = rsqrtf(q * (1.0f / 256.0f) - mu * mu + 1e-5f);
  }
#pragma unroll
  for (int tt = 0; tt < 16; ++tt) {
    const int c = tt * 16 + l15;
    const float g = g_ln[c], be = b_ln[c];
    float4 o;
    o.x = (acc[tt][0] - mean[0]) * rstd[0] * g + be;
    o.y = (acc[tt][1] - mean[1]) * rstd[1] * g + be;
    o.z = (acc[tt][2] - mean[2]) * rstd[2] * g + be;
    o.w = (acc[tt][3] - mean[3]) * rstd[3] * g + be;
    *(float4*)(out + (size_t)(b * 256 + c) * 16384 + n0 + w * 16 + l4 * 4) = o;
  }
}

// ---------------------------------------------------------------------------
extern "C" void kernel_launch(void* const* d_in, const int* in_sizes, int n_in,
                              void* d_out, int out_size, void* d_ws, size_t ws_size,
                              hipStream_t stream) {
  (void)in_sizes; (void)n_in; (void)out_size;
  const float* x   = (const float*)d_in[0];
  const float* Wq  = (const float*)d_in[1];
  const float* bq  = (const float*)d_in[2];
  const float* Wk  = (const float*)d_in[3];
  const float* bk  = (const float*)d_in[4];
  const float* Wv  = (const float*)d_in[5];
  const float* bv  = (const float*)d_in[6];
  const float* gK  = (const float*)d_in[7];
  const float* bK  = (const float*)d_in[8];
  const float* gV  = (const float*)d_in[9];
  const float* bV  = (const float*)d_in[10];
  const float* gln = (const float*)d_in[11];
  const float* bln = (const float*)d_in[12];
  float* out = (float*)d_out;

  // Per-batch: xT 8MB + W2bf 128K + W2f 256K + scores 32K + b2 1K + Py2 128K
  //            + Px2 128K = 9,077,760 B. Shared: Wk/Wv bf 256K + K-tables 256K.
  const size_t PB = 16384ULL * 256 * 2;
  const size_t PERZ = PB + 131072 + 262144 + 32768 + 1024 + 131072 + 131072;
  const size_t SHARED = 262144 + 262144;
  int g = 8;
  while (g > 1 && ws_size < (size_t)g * PERZ + SHARED) g >>= 1;
  // g=1 needs 9,602,048 B <= proven-safe 18,096,128 B.

  char* p = (char*)d_ws;
  ushort* xT    = (ushort*)p; p += (size_t)g * PB;
  ushort* Wkbf  = (ushort*)p; p += 131072;
  ushort* Wvbf  = (ushort*)p; p += 131072;
  float*  PyKb  = (float*)p;  p += 131072;
  float*  PxKT  = (float*)p;  p += 131072;
  ushort* W2bf  = (ushort*)p; p += (size_t)g * 131072;
  float*  W2f   = (float*)p;  p += (size_t)g * 262144;
  float*  Py2b  = (float*)p;  p += (size_t)g * 131072;
  float*  Px2T  = (float*)p;  p += (size_t)g * 131072;
  float*  scores = (float*)p; p += (size_t)g * 32768;
  float*  b2    = (float*)p;

  prep_w<<<dim3(64), 256, 0, stream>>>(Wk, Wv, Wkbf, Wvbf);
  poswk<<<dim3(128), 256, 0, stream>>>(Wk, bk, PyKb, PxKT);
  for (int b0 = 0; b0 < 8; b0 += g) {
    hipMemsetAsync(scores, 0, (size_t)g * 32768, stream);
    prep_qx<<<dim3(256, g), 256, 0, stream>>>(x, xT, b0);
    kv_scores<<<dim3(32, 2, g), 256, 0, stream>>>(xT, Wkbf, Wvbf, bv, gK, bK,
                                                  gV, bV, PyKb, PxKT, scores);
    w2_kernel<<<dim3(257, g), 256, 0, stream>>>(Wq, bq, scores, W2bf, W2f, b2);
    posw2<<<dim3(128, g), 256, 0, stream>>>(W2f, b2, Py2b, Px2T);
    out_kernel<<<dim3(256, g), 256, 0, stream>>>(xT, W2bf, Py2b, Px2T, gln, bln,
                                                 out, b0);
  }
}